// Round 2
// baseline (1004.760 us; speedup 1.0000x reference)
//
#include <hip/hip_runtime.h>
#include <math.h>

#define RES   1024
#define FEATC 12
#define CBN   32
#define H_IMG 1080
#define W_IMG 1920
#define NPIX  (H_IMG * W_IMG)
#define PPB   512   // pixels per block: 2 rounds of 256, compacted in LDS

__global__ __launch_bounds__(256, 4) void sky_kernel(
    const float* __restrict__ rays_d,   // [NPIX,3]
    const int*   __restrict__ mask,     // [NPIX]
    const float* __restrict__ cube,     // [6,RES,RES,12]
    const float* __restrict__ cb,       // [32,12]
    const float* __restrict__ W1,       // [15,32]
    const float* __restrict__ b1,       // [32]
    const float* __restrict__ W2,       // [32,32]
    const float* __restrict__ b2,       // [32]
    const float* __restrict__ W3,       // [32,3]
    const float* __restrict__ b3,       // [3]
    float*       __restrict__ out)      // [3,NPIX]
{
    __shared__ float  sW1[15 * 32];
    __shared__ float  sb1[32];
    __shared__ float  sW2[32 * 32];
    __shared__ float  sb2[32];
    __shared__ float  sW3[32 * 3];
    __shared__ float  sb3[3];
    __shared__ float  sCB[CBN * FEATC];     // f32 codebook (straight-through path, bit-exact)
    __shared__ double sCBd[CBN * FEATC];    // f64 codebook (exact f32->f64, argmin diff-form)
    __shared__ float  sRR[PPB * 3];         // phase2 in: compacted rays; phase2 out: rgb (slot-private)
    __shared__ short  sPos[PPB];            // original slot -> compacted pos, -1 if masked
    __shared__ int    sCnt;

    const int tid = threadIdx.x;

    for (int t = tid; t < 15 * 32; t += 256) sW1[t] = W1[t];
    for (int t = tid; t < 32;      t += 256) sb1[t] = b1[t];
    for (int t = tid; t < 32 * 32; t += 256) sW2[t] = W2[t];
    for (int t = tid; t < 32;      t += 256) sb2[t] = b2[t];
    for (int t = tid; t < 32 * 3;  t += 256) sW3[t] = W3[t];
    for (int t = tid; t < 3;       t += 256) sb3[t] = b3[t];
    for (int t = tid; t < CBN * FEATC; t += 256) {
        const float v = cb[t];
        sCB[t]  = v;
        sCBd[t] = (double)v;   // exact conversion: diff-form decisions identical to f32-source
    }
    if (tid == 0) sCnt = 0;
    __syncthreads();

    // ---- Phase 1: compact active pixels into LDS; record slot->pos map ----
    const int base = blockIdx.x * PPB;     // grid exact: NPIX = 4050*512
    const int lane = tid & 63;

    #pragma unroll
    for (int r = 0; r < 2; ++r) {
        const int o = r * 256 + tid;
        const int i = base + o;
        const bool ok = (mask[i] != 0);
        const float x = rays_d[3 * i + 0];
        const float y = rays_d[3 * i + 1];
        const float z = rays_d[3 * i + 2];

        const unsigned long long bal = __ballot(ok);
        const int pre  = __popcll(bal & ((1ull << lane) - 1ull));
        const int wcnt = __popcll(bal);
        int wbase = 0;
        if (lane == 0) wbase = atomicAdd(&sCnt, wcnt);
        wbase = __shfl(wbase, 0, 64);

        const int p = ok ? (wbase + pre) : -1;
        sPos[o] = (short)p;
        if (ok) {
            sRR[3 * p + 0] = x;
            sRR[3 * p + 1] = y;
            sRR[3 * p + 2] = z;
        }
    }
    __syncthreads();
    const int cnt = sCnt;

    // ---- Phase 2: full-lane processing of compacted pixels ----
    for (int j = tid; j < cnt; j += 256) {
        const float x = sRR[3 * j + 0];
        const float y = sRR[3 * j + 1];
        const float z = sRR[3 * j + 2];

        const float ax = fabsf(x), ay = fabsf(y), az = fabsf(z);
        const bool is_x = (ax >= ay) && (ax >= az);
        const bool is_y = (!is_x) && (ay >= az);

        int face; float ma, u, v;
        if (is_x) {
            face = (x >= 0.0f) ? 0 : 1;
            ma = ax;
            u = (x >= 0.0f) ? -z : z;
            v = -y;
        } else if (is_y) {
            face = (y >= 0.0f) ? 2 : 3;
            ma = ay;
            u = x;
            v = (y >= 0.0f) ? z : -z;
        } else {
            face = (z >= 0.0f) ? 4 : 5;
            ma = az;
            u = (z >= 0.0f) ? x : -x;
            v = -y;
        }

        // s = (u / (ma + eps) + 1.0) * 0.5 * R - 0.5, each op individually rounded
        const float denom = __fadd_rn(ma, 1e-9f);
        const float s = __fsub_rn(__fmul_rn(__fmul_rn(__fadd_rn(__fdiv_rn(u, denom), 1.0f), 0.5f), (float)RES), 0.5f);
        const float t = __fsub_rn(__fmul_rn(__fmul_rn(__fadd_rn(__fdiv_rn(v, denom), 1.0f), 0.5f), (float)RES), 0.5f);

        const float x0f = floorf(s);
        const float y0f = floorf(t);
        const float fx = __fsub_rn(s, x0f);
        const float fy = __fsub_rn(t, y0f);

        int x0i = (int)x0f; x0i = min(max(x0i, 0), RES - 1);
        int x1i = min(x0i + 1, RES - 1);
        int y0i = (int)y0f; y0i = min(max(y0i, 0), RES - 1);
        int y1i = min(y0i + 1, RES - 1);

        const size_t fbase = (size_t)face * RES * RES;
        const float4* p00 = (const float4*)(cube + (fbase + (size_t)y0i * RES + x0i) * FEATC);
        const float4* p01 = (const float4*)(cube + (fbase + (size_t)y0i * RES + x1i) * FEATC);
        const float4* p10 = (const float4*)(cube + (fbase + (size_t)y1i * RES + x0i) * FEATC);
        const float4* p11 = (const float4*)(cube + (fbase + (size_t)y1i * RES + x1i) * FEATC);

        // bilinear, fused: exactly the reference's op order per element
        const float omfx = __fsub_rn(1.0f, fx);
        const float omfy = __fsub_rn(1.0f, fy);
        float feat[FEATC];
        #pragma unroll
        for (int q4 = 0; q4 < 3; ++q4) {
            const float4 a  = p00[q4];
            const float4 b  = p01[q4];
            const float4 c  = p10[q4];
            const float4 d4 = p11[q4];
            {
                const float top = __fadd_rn(__fmul_rn(a.x, omfx), __fmul_rn(b.x, fx));
                const float bot = __fadd_rn(__fmul_rn(c.x, omfx), __fmul_rn(d4.x, fx));
                feat[4 * q4 + 0] = __fadd_rn(__fmul_rn(top, omfy), __fmul_rn(bot, fy));
            }
            {
                const float top = __fadd_rn(__fmul_rn(a.y, omfx), __fmul_rn(b.y, fx));
                const float bot = __fadd_rn(__fmul_rn(c.y, omfx), __fmul_rn(d4.y, fx));
                feat[4 * q4 + 1] = __fadd_rn(__fmul_rn(top, omfy), __fmul_rn(bot, fy));
            }
            {
                const float top = __fadd_rn(__fmul_rn(a.z, omfx), __fmul_rn(b.z, fx));
                const float bot = __fadd_rn(__fmul_rn(c.z, omfx), __fmul_rn(d4.z, fx));
                feat[4 * q4 + 2] = __fadd_rn(__fmul_rn(top, omfy), __fmul_rn(bot, fy));
            }
            {
                const float top = __fadd_rn(__fmul_rn(a.w, omfx), __fmul_rn(b.w, fx));
                const float bot = __fadd_rn(__fmul_rn(c.w, omfx), __fmul_rn(d4.w, fx));
                feat[4 * q4 + 3] = __fadd_rn(__fmul_rn(top, omfy), __fmul_rn(bot, fy));
            }
        }

        // argmin in fp64 diff-form (decision-identical to round-0 known-good);
        // serial d2 chain keeps register pressure minimal.
        int best = 0;
        double bestd = 1e300;
        for (int jj = 0; jj < CBN; ++jj) {
            double d2 = 0.0;
            #pragma unroll
            for (int k = 0; k < FEATC; ++k) {
                const double diff = (double)feat[k] - sCBd[jj * FEATC + k];
                d2 = fma(diff, diff, d2);
            }
            if (d2 < bestd) { bestd = d2; best = jj; }
        }

        // straight-through: q = feat + (cb[best] - feat), elementwise rounding
        float hin[15];
        #pragma unroll
        for (int k = 0; k < FEATC; ++k)
            hin[k] = __fadd_rn(feat[k], __fsub_rn(sCB[best * FEATC + k], feat[k]));
        hin[12] = x; hin[13] = y; hin[14] = z;

        float h1[32];
        #pragma unroll
        for (int k = 0; k < 32; ++k) {
            float a = sb1[k];
            #pragma unroll
            for (int jw = 0; jw < 15; ++jw) a += hin[jw] * sW1[jw * 32 + k];
            h1[k] = fmaxf(a, 0.0f);
        }

        float h2[32];
        #pragma unroll
        for (int k = 0; k < 32; ++k) {
            float a = sb2[k];
            #pragma unroll
            for (int jw = 0; jw < 32; ++jw) a += h1[jw] * sW2[jw * 32 + k];
            h2[k] = fmaxf(a, 0.0f);
        }

        float rgb[3];
        #pragma unroll
        for (int c = 0; c < 3; ++c) {
            float a = sb3[c];
            #pragma unroll
            for (int jw = 0; jw < 32; ++jw) a += h2[jw] * sW3[jw * 3 + c];
            float r = 1.0f / (1.0f + expf(-a));
            rgb[c] = fminf(fmaxf(r, 0.0f), 1.0f);
        }

        // slot-private overwrite of the ray buffer with the result
        sRR[3 * j + 0] = rgb[0];
        sRR[3 * j + 1] = rgb[1];
        sRR[3 * j + 2] = rgb[2];
    }
    __syncthreads();

    // ---- Phase 3: coalesced writeback in original pixel order ----
    #pragma unroll
    for (int r = 0; r < 2; ++r) {
        const int o = r * 256 + tid;
        const int i = base + o;
        const int p = (int)sPos[o];
        float r0 = 0.0f, r1 = 0.0f, r2 = 0.0f;
        if (p >= 0) {
            r0 = sRR[3 * p + 0];
            r1 = sRR[3 * p + 1];
            r2 = sRR[3 * p + 2];
        }
        out[0 * (size_t)NPIX + i] = r0;
        out[1 * (size_t)NPIX + i] = r1;
        out[2 * (size_t)NPIX + i] = r2;
    }
}

extern "C" void kernel_launch(void* const* d_in, const int* in_sizes, int n_in,
                              void* d_out, int out_size, void* d_ws, size_t ws_size,
                              hipStream_t stream) {
    (void)in_sizes; (void)n_in; (void)out_size; (void)d_ws; (void)ws_size;
    const float* rays_d = (const float*)d_in[0];
    const int*   mask   = (const int*)d_in[1];
    const float* cube   = (const float*)d_in[2];
    const float* cb     = (const float*)d_in[3];
    const float* W1     = (const float*)d_in[4];
    const float* b1     = (const float*)d_in[5];
    const float* W2     = (const float*)d_in[6];
    const float* b2     = (const float*)d_in[7];
    const float* W3     = (const float*)d_in[8];
    const float* b3     = (const float*)d_in[9];
    float* out = (float*)d_out;

    const int block = 256;
    const int grid  = NPIX / PPB;   // 4050 exactly (2073600 = 4050*512)
    sky_kernel<<<grid, block, 0, stream>>>(rays_d, mask, cube, cb,
                                           W1, b1, W2, b2, W3, b3, out);
}

// Round 3
// 863.494 us; speedup vs baseline: 1.1636x; 1.1636x over previous
//
#include <hip/hip_runtime.h>
#include <math.h>

#define RES   1024
#define FEATC 12
#define CBN   32
#define H_IMG 1080
#define W_IMG 1920
#define NPIX  (H_IMG * W_IMG)
#define PPB   512   // pixels per block: 2 rounds of 256, compacted in LDS

__global__ __launch_bounds__(256, 2) void sky_kernel(
    const float* __restrict__ rays_d,   // [NPIX,3]
    const int*   __restrict__ mask,     // [NPIX]
    const float* __restrict__ cube,     // [6,RES,RES,12]
    const float* __restrict__ cb,       // [32,12]
    const float* __restrict__ W1,       // [15,32]
    const float* __restrict__ b1,       // [32]
    const float* __restrict__ W2,       // [32,32]
    const float* __restrict__ b2,       // [32]
    const float* __restrict__ W3,       // [32,3]
    const float* __restrict__ b3,       // [3]
    float*       __restrict__ out)      // [3,NPIX]
{
    __shared__ float  sW1[15 * 32];
    __shared__ float  sb1[32];
    __shared__ float  sW2[32 * 32];
    __shared__ float  sb2[32];
    __shared__ float  sW3[32 * 3];
    __shared__ float  sb3[3];
    __shared__ float  sCB[CBN * FEATC];     // f32 codebook (straight-through path, bit-exact)
    __shared__ double sCBd[CBN * FEATC];    // f64 codebook (exact f32->f64, argmin diff-form)
    __shared__ float  sRR[PPB * 3];         // phase2 in: compacted rays; phase2 out: rgb (slot-private)
    __shared__ short  sPos[PPB];            // original slot -> compacted pos, -1 if masked
    __shared__ int    sCnt;

    const int tid = threadIdx.x;

    for (int t = tid; t < 15 * 32; t += 256) sW1[t] = W1[t];
    for (int t = tid; t < 32;      t += 256) sb1[t] = b1[t];
    for (int t = tid; t < 32 * 32; t += 256) sW2[t] = W2[t];
    for (int t = tid; t < 32;      t += 256) sb2[t] = b2[t];
    for (int t = tid; t < 32 * 3;  t += 256) sW3[t] = W3[t];
    for (int t = tid; t < 3;       t += 256) sb3[t] = b3[t];
    for (int t = tid; t < CBN * FEATC; t += 256) {
        const float v = cb[t];
        sCB[t]  = v;
        sCBd[t] = (double)v;   // exact conversion: diff-form decisions identical to f32-source
    }
    if (tid == 0) sCnt = 0;
    __syncthreads();

    // ---- Phase 1: compact active pixels into LDS; record slot->pos map ----
    const int base = blockIdx.x * PPB;     // grid exact: NPIX = 4050*512
    const int lane = tid & 63;

    #pragma unroll
    for (int r = 0; r < 2; ++r) {
        const int o = r * 256 + tid;
        const int i = base + o;
        const bool ok = (mask[i] != 0);
        const float x = rays_d[3 * i + 0];
        const float y = rays_d[3 * i + 1];
        const float z = rays_d[3 * i + 2];

        const unsigned long long bal = __ballot(ok);
        const int pre  = __popcll(bal & ((1ull << lane) - 1ull));
        const int wcnt = __popcll(bal);
        int wbase = 0;
        if (lane == 0) wbase = atomicAdd(&sCnt, wcnt);
        wbase = __shfl(wbase, 0, 64);

        const int p = ok ? (wbase + pre) : -1;
        sPos[o] = (short)p;
        if (ok) {
            sRR[3 * p + 0] = x;
            sRR[3 * p + 1] = y;
            sRR[3 * p + 2] = z;
        }
    }
    __syncthreads();
    const int cnt = sCnt;

    // ---- Phase 2: full-lane processing of compacted pixels ----
    for (int j = tid; j < cnt; j += 256) {
        const float x = sRR[3 * j + 0];
        const float y = sRR[3 * j + 1];
        const float z = sRR[3 * j + 2];

        const float ax = fabsf(x), ay = fabsf(y), az = fabsf(z);
        const bool is_x = (ax >= ay) && (ax >= az);
        const bool is_y = (!is_x) && (ay >= az);

        int face; float ma, u, v;
        if (is_x) {
            face = (x >= 0.0f) ? 0 : 1;
            ma = ax;
            u = (x >= 0.0f) ? -z : z;
            v = -y;
        } else if (is_y) {
            face = (y >= 0.0f) ? 2 : 3;
            ma = ay;
            u = x;
            v = (y >= 0.0f) ? z : -z;
        } else {
            face = (z >= 0.0f) ? 4 : 5;
            ma = az;
            u = (z >= 0.0f) ? x : -x;
            v = -y;
        }

        // s = (u / (ma + eps) + 1.0) * 0.5 * R - 0.5, each op individually rounded
        const float denom = __fadd_rn(ma, 1e-9f);
        const float s = __fsub_rn(__fmul_rn(__fmul_rn(__fadd_rn(__fdiv_rn(u, denom), 1.0f), 0.5f), (float)RES), 0.5f);
        const float t = __fsub_rn(__fmul_rn(__fmul_rn(__fadd_rn(__fdiv_rn(v, denom), 1.0f), 0.5f), (float)RES), 0.5f);

        const float x0f = floorf(s);
        const float y0f = floorf(t);
        const float fx = __fsub_rn(s, x0f);
        const float fy = __fsub_rn(t, y0f);

        int x0i = (int)x0f; x0i = min(max(x0i, 0), RES - 1);
        int x1i = min(x0i + 1, RES - 1);
        int y0i = (int)y0f; y0i = min(max(y0i, 0), RES - 1);
        int y1i = min(y0i + 1, RES - 1);

        const size_t fbase = (size_t)face * RES * RES;
        const float4* p00 = (const float4*)(cube + (fbase + (size_t)y0i * RES + x0i) * FEATC);
        const float4* p01 = (const float4*)(cube + (fbase + (size_t)y0i * RES + x1i) * FEATC);
        const float4* p10 = (const float4*)(cube + (fbase + (size_t)y1i * RES + x0i) * FEATC);
        const float4* p11 = (const float4*)(cube + (fbase + (size_t)y1i * RES + x1i) * FEATC);

        // bilinear, fused: exactly the reference's op order per element
        const float omfx = __fsub_rn(1.0f, fx);
        const float omfy = __fsub_rn(1.0f, fy);
        float feat[FEATC];
        #pragma unroll
        for (int q4 = 0; q4 < 3; ++q4) {
            const float4 a  = p00[q4];
            const float4 b  = p01[q4];
            const float4 c  = p10[q4];
            const float4 d4 = p11[q4];
            {
                const float top = __fadd_rn(__fmul_rn(a.x, omfx), __fmul_rn(b.x, fx));
                const float bot = __fadd_rn(__fmul_rn(c.x, omfx), __fmul_rn(d4.x, fx));
                feat[4 * q4 + 0] = __fadd_rn(__fmul_rn(top, omfy), __fmul_rn(bot, fy));
            }
            {
                const float top = __fadd_rn(__fmul_rn(a.y, omfx), __fmul_rn(b.y, fx));
                const float bot = __fadd_rn(__fmul_rn(c.y, omfx), __fmul_rn(d4.y, fx));
                feat[4 * q4 + 1] = __fadd_rn(__fmul_rn(top, omfy), __fmul_rn(bot, fy));
            }
            {
                const float top = __fadd_rn(__fmul_rn(a.z, omfx), __fmul_rn(b.z, fx));
                const float bot = __fadd_rn(__fmul_rn(c.z, omfx), __fmul_rn(d4.z, fx));
                feat[4 * q4 + 2] = __fadd_rn(__fmul_rn(top, omfy), __fmul_rn(bot, fy));
            }
            {
                const float top = __fadd_rn(__fmul_rn(a.w, omfx), __fmul_rn(b.w, fx));
                const float bot = __fadd_rn(__fmul_rn(c.w, omfx), __fmul_rn(d4.w, fx));
                feat[4 * q4 + 3] = __fadd_rn(__fmul_rn(top, omfy), __fmul_rn(bot, fy));
            }
        }

        // argmin in fp64 diff-form (decision-identical to round-0 known-good);
        // serial d2 chain keeps register pressure minimal.
        int best = 0;
        double bestd = 1e300;
        for (int jj = 0; jj < CBN; ++jj) {
            double d2 = 0.0;
            #pragma unroll
            for (int k = 0; k < FEATC; ++k) {
                const double diff = (double)feat[k] - sCBd[jj * FEATC + k];
                d2 = fma(diff, diff, d2);
            }
            if (d2 < bestd) { bestd = d2; best = jj; }
        }

        // straight-through: q = feat + (cb[best] - feat), elementwise rounding
        float hin[15];
        #pragma unroll
        for (int k = 0; k < FEATC; ++k)
            hin[k] = __fadd_rn(feat[k], __fsub_rn(sCB[best * FEATC + k], feat[k]));
        hin[12] = x; hin[13] = y; hin[14] = z;

        float h1[32];
        #pragma unroll
        for (int k = 0; k < 32; ++k) {
            float a = sb1[k];
            #pragma unroll
            for (int jw = 0; jw < 15; ++jw) a += hin[jw] * sW1[jw * 32 + k];
            h1[k] = fmaxf(a, 0.0f);
        }

        float h2[32];
        #pragma unroll
        for (int k = 0; k < 32; ++k) {
            float a = sb2[k];
            #pragma unroll
            for (int jw = 0; jw < 32; ++jw) a += h1[jw] * sW2[jw * 32 + k];
            h2[k] = fmaxf(a, 0.0f);
        }

        float rgb[3];
        #pragma unroll
        for (int c = 0; c < 3; ++c) {
            float a = sb3[c];
            #pragma unroll
            for (int jw = 0; jw < 32; ++jw) a += h2[jw] * sW3[jw * 3 + c];
            float r = 1.0f / (1.0f + expf(-a));
            rgb[c] = fminf(fmaxf(r, 0.0f), 1.0f);
        }

        // slot-private overwrite of the ray buffer with the result
        sRR[3 * j + 0] = rgb[0];
        sRR[3 * j + 1] = rgb[1];
        sRR[3 * j + 2] = rgb[2];
    }
    __syncthreads();

    // ---- Phase 3: coalesced writeback in original pixel order ----
    #pragma unroll
    for (int r = 0; r < 2; ++r) {
        const int o = r * 256 + tid;
        const int i = base + o;
        const int p = (int)sPos[o];
        float r0 = 0.0f, r1 = 0.0f, r2 = 0.0f;
        if (p >= 0) {
            r0 = sRR[3 * p + 0];
            r1 = sRR[3 * p + 1];
            r2 = sRR[3 * p + 2];
        }
        out[0 * (size_t)NPIX + i] = r0;
        out[1 * (size_t)NPIX + i] = r1;
        out[2 * (size_t)NPIX + i] = r2;
    }
}

extern "C" void kernel_launch(void* const* d_in, const int* in_sizes, int n_in,
                              void* d_out, int out_size, void* d_ws, size_t ws_size,
                              hipStream_t stream) {
    (void)in_sizes; (void)n_in; (void)out_size; (void)d_ws; (void)ws_size;
    const float* rays_d = (const float*)d_in[0];
    const int*   mask   = (const int*)d_in[1];
    const float* cube   = (const float*)d_in[2];
    const float* cb     = (const float*)d_in[3];
    const float* W1     = (const float*)d_in[4];
    const float* b1     = (const float*)d_in[5];
    const float* W2     = (const float*)d_in[6];
    const float* b2     = (const float*)d_in[7];
    const float* W3     = (const float*)d_in[8];
    const float* b3     = (const float*)d_in[9];
    float* out = (float*)d_out;

    const int block = 256;
    const int grid  = NPIX / PPB;   // 4050 exactly (2073600 = 4050*512)
    sky_kernel<<<grid, block, 0, stream>>>(rays_d, mask, cube, cb,
                                           W1, b1, W2, b2, W3, b3, out);
}